// Round 11
// baseline (226.450 us; speedup 1.0000x reference)
//
#include <hip/hip_runtime.h>
#include <stdint.h>

typedef unsigned short u16;
typedef __attribute__((ext_vector_type(8))) short s16x8;   // 8 x bf16 (4 VGPRs)
typedef __attribute__((ext_vector_type(4))) float f32x4;   // MFMA accumulator

__device__ __forceinline__ f32x4 mfma16x16(s16x8 a, s16x8 b, f32x4 c) {
    return __builtin_amdgcn_mfma_f32_16x16x32_bf16(a, b, c, 0, 0, 0);
}

__device__ __forceinline__ u16 f2bf(float f) {
    union { float f; unsigned u; } c; c.f = f;
    unsigned u = c.u;
    return (u16)((u + 0x7FFFu + ((u >> 16) & 1u)) >> 16);   // RNE
}

// global -> LDS direct 16B load. LDS dest = wave-uniform base + lane*16.
__device__ __forceinline__ void gload16(const void* g, void* l) {
    auto gp = (const __attribute__((address_space(1))) unsigned int*)(g);
    auto lp = (__attribute__((address_space(3))) unsigned int*)(l);
    __builtin_amdgcn_global_load_lds(gp, lp, 16, 0, 0);
}

__device__ __forceinline__ void wave_sync() {
    __builtin_amdgcn_sched_barrier(0);
    asm volatile("s_waitcnt vmcnt(0) lgkmcnt(0)" ::: "memory");
    __builtin_amdgcn_sched_barrier(0);
    __builtin_amdgcn_s_barrier();
    __builtin_amdgcn_sched_barrier(0);
}

// ---------------------------------------------------------------------------
__global__ __launch_bounds__(256) void convert_x(
    const float* __restrict__ src, u16* __restrict__ dst, long n)
{
    const long stride = (long)gridDim.x * 256 * 8;
    for (long i = ((long)blockIdx.x * 256 + threadIdx.x) * 8; i < n; i += stride) {
        const float4 a = *(const float4*)(src + i);
        const float4 b = *(const float4*)(src + i + 4);
        u16 o[8] = { f2bf(a.x), f2bf(a.y), f2bf(a.z), f2bf(a.w),
                     f2bf(b.x), f2bf(b.y), f2bf(b.z), f2bf(b.w) };
        *(s16x8*)(dst + i) = *(const s16x8*)o;
    }
}

__global__ __launch_bounds__(256) void fill_sentinel(float* __restrict__ o, long n)
{
    const long stride = (long)gridDim.x * 256;
    for (long i = (long)blockIdx.x * 256 + threadIdx.x; i < n; i += stride)
        o[i] = 1.0f;
}

__global__ __launch_bounds__(256) void transpose_f32_bf16(
    const float* __restrict__ in, u16* __restrict__ out, int R, int C)
{
    __shared__ u16 t[32][33];
    const int c0 = blockIdx.x * 32, r0 = blockIdx.y * 32;
    const int tx = threadIdx.x & 31, ty = threadIdx.x >> 5;
#pragma unroll
    for (int i = 0; i < 32; i += 8)
        t[ty + i][tx] = f2bf(in[(long)(r0 + ty + i) * C + c0 + tx]);
    __syncthreads();
#pragma unroll
    for (int i = 0; i < 32; i += 8)
        out[(long)(c0 + ty + i) * R + r0 + tx] = t[tx][ty + i];
}

// ---------------------------------------------------------------------------
// 128x128 GEMM, 4 waves (2x2), 64 KB LDS -> 2 independent blocks/CU.
// Direct transcription of the R9 4-phase register-prefetch schedule with all
// counts halved; vmcnt ledger numerically identical (12 outstanding at the
// boundary, vmcnt(4) drains (t+1).h0+h1, leaves (t+2).h0 in flight).
// LDS regions: idx (t&1)*2+h, each 8 KB = 128 rows x 32 cols bf16 (64B rows),
// swizzle chunk ^= (row>>1)&3 -> 2-way (free) on ds_read_b128.
// Mid-barrier after ph1 = WAR guard before ph2/ph3 DMA into current h0.
// ---------------------------------------------------------------------------
template <int FP32OUT, int NT, int NBN>
__global__ __launch_bounds__(256, 2) void gemm128(
    const u16* __restrict__ A, const u16* __restrict__ BT,
    const float* __restrict__ bias, void* __restrict__ Cout,
    int N, int K)
{
    extern __shared__ char smem[];     // 65536: As 4x8KB | Bs 4x8KB
    char* const As = smem;
    char* const Bs = smem + 32768;

    const int tid  = threadIdx.x;
    const int lane = tid & 63;
    const int wid  = tid >> 6;
    const int rr   = lane & 15, g = lane >> 4;
    const int wr   = wid >> 1;      // 0..1 (M)
    const int wc   = wid & 1;       // 0..1 (N)

    const int nwg = gridDim.x;
    const int gsw = ((int)blockIdx.x & 7) * (nwg >> 3) + ((int)blockIdx.x >> 3);
    const long m0 = (long)(gsw / NBN) * 128;   // n-fastest within XCD
    const long n0 = (long)(gsw % NBN) * 128;

    // staging: pass p covers row p*64 + tid/4, chunk (tid&3)^((tid>>3)&3)
    const int cl = (tid & 3) ^ ((tid >> 3) & 3);
    const u16* pA[2]; const u16* pB[2];
#pragma unroll
    for (int p = 0; p < 2; ++p) {
        pA[p] = A  + (m0 + p * 64 + (tid >> 2)) * (long)K + cl * 8;
        pB[p] = BT + (n0 + p * 64 + (tid >> 2)) * (long)K + cl * 8;
    }
    const int sdst = wid * 1024;     // + p*4096 + region*8192

    const int xg   = (g ^ ((rr >> 1) & 3)) << 4;
    const int arow = (wr * 64 + rr) * 64 + xg;   // + mf*1024
    const int brow = (wc * 64 + rr) * 64 + xg;   // + nf*1024

#define STA(tt, h) { const long c_ = (long)(tt) * 64 + (h) * 32;              \
        char* d_ = As + (((tt) & 1) * 2 + (h)) * 8192 + sdst;                 \
        gload16(pA[0] + c_, d_); gload16(pA[1] + c_, d_ + 4096); }
#define STB(tt, h) { const long c_ = (long)(tt) * 64 + (h) * 32;              \
        char* d_ = Bs + (((tt) & 1) * 2 + (h)) * 8192 + sdst;                 \
        gload16(pB[0] + c_, d_); gload16(pB[1] + c_, d_ + 4096); }
#define SB() __builtin_amdgcn_sched_barrier(0)

    f32x4 acc[4][4] = {};

    // prologue: t0.h0(A,B), t0.h1(A,B), t1.h0(A,B) = 12 gloads
    STA(0, 0); STB(0, 0); STA(0, 1); STB(0, 1); STA(1, 0); STB(1, 0);
    asm volatile("s_waitcnt vmcnt(4)" ::: "memory");   // t0 fully landed
    SB(); __builtin_amdgcn_s_barrier(); SB();

    for (int t = 0; t < NT; ++t) {
        const int ab = (t & 1) * 16384;   // h0 at ab, h1 at ab+8192
        s16x8 fB0[4], fB1[4], fA0[2], fA1[2], fA2[2], fA3[2];

        // ---- ph0: read kk0 (B 4 + A 4); stage (t+1).h1-A; MFMA m01xkk0
#pragma unroll
        for (int n = 0; n < 4; ++n)
            fB0[n] = *(const s16x8*)(Bs + ab + brow + n * 1024);
#pragma unroll
        for (int m = 0; m < 2; ++m) {
            fA0[m] = *(const s16x8*)(As + ab + arow + m * 1024);
            fA1[m] = *(const s16x8*)(As + ab + arow + (m + 2) * 1024);
        }
        if (t + 1 < NT) STA(t + 1, 1);
        SB();
        __builtin_amdgcn_s_setprio(1);
#pragma unroll
        for (int m = 0; m < 2; ++m)
#pragma unroll
            for (int n = 0; n < 4; ++n)
                acc[m][n] = mfma16x16(fA0[m], fB0[n], acc[m][n]);
        __builtin_amdgcn_s_setprio(0);
        SB();

        // ---- ph1: read kk1 (B 4 + A m01 2); stage (t+1).h1-B; MFMA m23xkk0
#pragma unroll
        for (int n = 0; n < 4; ++n)
            fB1[n] = *(const s16x8*)(Bs + ab + 8192 + brow + n * 1024);
#pragma unroll
        for (int m = 0; m < 2; ++m)
            fA2[m] = *(const s16x8*)(As + ab + 8192 + arow + m * 1024);
        if (t + 1 < NT) STB(t + 1, 1);
        SB();
        __builtin_amdgcn_s_setprio(1);
#pragma unroll
        for (int m = 0; m < 2; ++m)
#pragma unroll
            for (int n = 0; n < 4; ++n)
                acc[m + 2][n] = mfma16x16(fA1[m], fB0[n], acc[m + 2][n]);
        __builtin_amdgcn_s_setprio(0);
        SB(); __builtin_amdgcn_s_barrier(); SB();   // kk0 region now free

        // ---- ph2: read kk1 A m23 (2); stage (t+2).h0-A; MFMA m01xkk1
#pragma unroll
        for (int m = 0; m < 2; ++m)
            fA3[m] = *(const s16x8*)(As + ab + 8192 + arow + (m + 2) * 1024);
        if (t + 2 < NT) STA(t + 2, 0);
        SB();
        __builtin_amdgcn_s_setprio(1);
#pragma unroll
        for (int m = 0; m < 2; ++m)
#pragma unroll
            for (int n = 0; n < 4; ++n)
                acc[m][n] = mfma16x16(fA2[m], fB1[n], acc[m][n]);
        __builtin_amdgcn_s_setprio(0);
        SB();

        // ---- ph3: stage (t+2).h0-B; MFMA m23xkk1
        if (t + 2 < NT) STB(t + 2, 0);
        SB();
        __builtin_amdgcn_s_setprio(1);
#pragma unroll
        for (int m = 0; m < 2; ++m)
#pragma unroll
            for (int n = 0; n < 4; ++n)
                acc[m + 2][n] = mfma16x16(fA3[m], fB1[n], acc[m + 2][n]);
        __builtin_amdgcn_s_setprio(0);
        SB();

        // ---- boundary: counted gate, barrier
        if (t < NT - 1) {
            if (t >= NT - 2) { asm volatile("s_waitcnt vmcnt(0)" ::: "memory"); }
            else             { asm volatile("s_waitcnt vmcnt(4)" ::: "memory"); }
            SB(); __builtin_amdgcn_s_barrier(); SB();
        }
    }
#undef STA
#undef STB
#undef SB

    // epilogue: n innermost (L2 write-merge); wave covers 64 contiguous cols
    float bv[4];
#pragma unroll
    for (int n = 0; n < 4; ++n)
        bv[n] = bias[n0 + wc * 64 + n * 16 + rr];
#pragma unroll
    for (int m = 0; m < 4; ++m) {
        const long rb = m0 + wr * 64 + m * 16 + g * 4;
#pragma unroll
        for (int r = 0; r < 4; ++r) {
            const long rowoff = (rb + r) * N + n0 + wc * 64 + rr;
#pragma unroll
            for (int n = 0; n < 4; ++n) {
                const float v = acc[m][n][r] + bv[n];
                if (FP32OUT) ((float*)Cout)[rowoff + n * 16] = v;
                else         ((u16*)Cout)[rowoff + n * 16] = f2bf(v);
            }
        }
    }
}

// ---------------------------------------------------------------------------
// R9 256x256 GEMM (proven): 4-phase register-prefetch, 8 waves, 128 KB LDS.
// ---------------------------------------------------------------------------
template <int FP32OUT, int NT, int NBN>
__global__ __launch_bounds__(512, 2) void gemm256(
    const u16* __restrict__ A, const u16* __restrict__ BT,
    const float* __restrict__ bias, void* __restrict__ Cout,
    int N, int K)
{
    extern __shared__ char smem[];          // 131072 B
    char* const As = smem;                  // [(t&1)*2 + h] * 16384
    char* const Bs = smem + 65536;

    const int tid  = threadIdx.x;
    const int lane = tid & 63;
    const int wid  = tid >> 6;
    const int rr   = lane & 15, g = lane >> 4;
    const int wr   = wid >> 2;
    const int wc   = wid & 3;

    const int nwg = gridDim.x;
    const int gsw = ((int)blockIdx.x & 7) * (nwg >> 3) + ((int)blockIdx.x >> 3);
    const long m0 = (long)(gsw / NBN) * 256;
    const long n0 = (long)(gsw % NBN) * 256;

    const int cl = (tid & 3) ^ ((tid >> 3) & 3);
    const u16* pA0 = A  + (m0 + (tid >> 2)) * (long)K + cl * 8;
    const u16* pA1 = pA0 + 128 * (long)K;
    const u16* pB0 = BT + (n0 + (tid >> 2)) * (long)K + cl * 8;
    const u16* pB1 = pB0 + 128 * (long)K;
    const int sdst = wid * 1024;

    const int xg    = (g ^ ((rr >> 1) & 3)) << 4;
    const int arow  = (wr * 128 + rr) * 64 + xg;
    const int brow  = (wc * 64  + rr) * 64 + xg;

#define STA(tt, h) { const long c_ = (long)(tt) * 64 + (h) * 32;              \
        char* d_ = As + (((tt) & 1) * 2 + (h)) * 16384 + sdst;                \
        gload16(pA0 + c_, d_); gload16(pA1 + c_, d_ + 8192); }
#define STB(tt, h) { const long c_ = (long)(tt) * 64 + (h) * 32;              \
        char* d_ = Bs + (((tt) & 1) * 2 + (h)) * 16384 + sdst;                \
        gload16(pB0 + c_, d_); gload16(pB1 + c_, d_ + 8192); }
#define SB() __builtin_amdgcn_sched_barrier(0)

    f32x4 acc[8][4] = {};

    STA(0, 0); STB(0, 0); STA(0, 1); STB(0, 1); STA(1, 0); STB(1, 0);
    asm volatile("s_waitcnt vmcnt(4)" ::: "memory");
    SB(); __builtin_amdgcn_s_barrier(); SB();

    for (int t = 0; t < NT; ++t) {
        const int ab = (t & 1) * 32768;
        s16x8 fB0[4], fA0[4], fA1[4], fB1[4], fA2[4], fA3[4];

#pragma unroll
        for (int n = 0; n < 4; ++n)
            fB0[n] = *(const s16x8*)(Bs + ab + brow + n * 1024);
#pragma unroll
        for (int m = 0; m < 4; ++m)
            fA0[m] = *(const s16x8*)(As + ab + arow + m * 1024);
#pragma unroll
        for (int m = 0; m < 4; ++m)
            fA1[m] = *(const s16x8*)(As + ab + arow + (m + 4) * 1024);
        if (t + 1 < NT) STA(t + 1, 1);
        SB();
        __builtin_amdgcn_s_setprio(1);
#pragma unroll
        for (int m = 0; m < 4; ++m)
#pragma unroll
            for (int n = 0; n < 4; ++n)
                acc[m][n] = mfma16x16(fA0[m], fB0[n], acc[m][n]);
        __builtin_amdgcn_s_setprio(0);
        SB();

#pragma unroll
        for (int n = 0; n < 4; ++n)
            fB1[n] = *(const s16x8*)(Bs + ab + 16384 + brow + n * 1024);
#pragma unroll
        for (int m = 0; m < 4; ++m)
            fA2[m] = *(const s16x8*)(As + ab + 16384 + arow + m * 1024);
        if (t + 1 < NT) STB(t + 1, 1);
        SB();
        __builtin_amdgcn_s_setprio(1);
#pragma unroll
        for (int m = 0; m < 4; ++m)
#pragma unroll
            for (int n = 0; n < 4; ++n)
                acc[m + 4][n] = mfma16x16(fA1[m], fB0[n], acc[m + 4][n]);
        __builtin_amdgcn_s_setprio(0);
        SB(); __builtin_amdgcn_s_barrier(); SB();

#pragma unroll
        for (int m = 0; m < 4; ++m)
            fA3[m] = *(const s16x8*)(As + ab + 16384 + arow + (m + 4) * 1024);
        if (t + 2 < NT) STA(t + 2, 0);
        SB();
        __builtin_amdgcn_s_setprio(1);
#pragma unroll
        for (int m = 0; m < 4; ++m)
#pragma unroll
            for (int n = 0; n < 4; ++n)
                acc[m][n] = mfma16x16(fA2[m], fB1[n], acc[m][n]);
        __builtin_amdgcn_s_setprio(0);
        SB();

        if (t + 2 < NT) STB(t + 2, 0);
        SB();
        __builtin_amdgcn_s_setprio(1);
#pragma unroll
        for (int m = 0; m < 4; ++m)
#pragma unroll
            for (int n = 0; n < 4; ++n)
                acc[m + 4][n] = mfma16x16(fA3[m], fB1[n], acc[m + 4][n]);
        __builtin_amdgcn_s_setprio(0);
        SB();

        if (t < NT - 1) {
            if (t >= NT - 2) { asm volatile("s_waitcnt vmcnt(0)" ::: "memory"); }
            else             { asm volatile("s_waitcnt vmcnt(4)" ::: "memory"); }
            SB(); __builtin_amdgcn_s_barrier(); SB();
        }
    }
#undef STA
#undef STB
#undef SB

    float bv[4];
#pragma unroll
    for (int n = 0; n < 4; ++n)
        bv[n] = bias[n0 + wc * 64 + n * 16 + rr];
#pragma unroll
    for (int m = 0; m < 8; ++m) {
        const long rb = m0 + wr * 128 + m * 16 + g * 4;
#pragma unroll
        for (int r = 0; r < 4; ++r) {
            const long rowoff = (rb + r) * N + n0 + wc * 64 + rr;
#pragma unroll
            for (int n = 0; n < 4; ++n) {
                const float v = acc[m][n][r] + bv[n];
                if (FP32OUT) ((float*)Cout)[rowoff + n * 16] = v;
                else         ((u16*)Cout)[rowoff + n * 16] = f2bf(v);
            }
        }
    }
}

// ---------------------------------------------------------------------------
// Factored attention: one wave per (b, h, p). Attention over NB=64 blocks.
// ---------------------------------------------------------------------------
__global__ __launch_bounds__(64) void attn_blocks(
    const u16* __restrict__ qkv, u16* __restrict__ o)
{
    __shared__ u16 Vlds[64 * 64];
    __shared__ u16 Plds[64 * 72];
    const int bid = blockIdx.x;
    const int b = bid >> 11;
    const int h = (bid >> 7) & 15;
    const int p = bid & 127;
    const int lane = threadIdx.x;
    const int rr = lane & 15, g = lane >> 4;
    const long NSTR = 128L * 3072;
    const long base = ((long)b * 8192 + p) * 3072 + h * 64;

    {
        const int vrow = lane >> 3;
        const int vchunk = (lane & 7) ^ (vrow & 7);
#pragma unroll
        for (int q = 0; q < 8; ++q)
            gload16(qkv + base + (long)(q * 8 + vrow) * NSTR + 2048 + vchunk * 8,
                    (char*)Vlds + q * 1024);
    }

    s16x8 kf[4][2], qf[4][2];
#pragma unroll
    for (int t = 0; t < 4; ++t)
#pragma unroll
        for (int ks = 0; ks < 2; ++ks) {
            const long roff = base + (long)(t * 16 + rr) * NSTR + ks * 32 + g * 8;
            kf[t][ks] = *(const s16x8*)(qkv + roff + 1024);
            qf[t][ks] = *(const s16x8*)(qkv + roff);
        }

    f32x4 T[4][4] = {};
#pragma unroll
    for (int ks = 0; ks < 2; ++ks)
#pragma unroll
        for (int i = 0; i < 4; ++i)
#pragma unroll
            for (int jn = 0; jn < 4; ++jn)
                T[i][jn] = mfma16x16(kf[i][ks], qf[jn][ks], T[i][jn]);

    const float scale = 0.125f;
#pragma unroll
    for (int jn = 0; jn < 4; ++jn) {
        const int n = jn * 16 + rr;
        float pv[16];
        float mx = -3e38f;
#pragma unroll
        for (int i = 0; i < 4; ++i)
#pragma unroll
            for (int r = 0; r < 4; ++r) {
                const int m = i * 16 + g * 4 + r;
                const float s = (m <= n) ? T[i][jn][r] * scale : -3e38f;
                pv[i * 4 + r] = s;
                mx = fmaxf(mx, s);
            }
        mx = fmaxf(mx, __shfl_xor(mx, 16));
        mx = fmaxf(mx, __shfl_xor(mx, 32));
        float sum = 0.f;
#pragma unroll
        for (int t = 0; t < 16; ++t) {
            const float e = (pv[t] > -1e30f) ? __expf(pv[t] - mx) : 0.f;
            pv[t] = e;
            sum += e;
        }
        sum += __shfl_xor(sum, 16);
        sum += __shfl_xor(sum, 32);
        const float inv = 1.f / sum;
#pragma unroll
        for (int i = 0; i < 4; ++i)
#pragma unroll
            for (int rp = 0; rp < 2; ++rp) {
                const int m = i * 16 + g * 4 + rp * 2;
                const unsigned lo = f2bf(pv[i * 4 + rp * 2] * inv);
                const unsigned hi = f2bf(pv[i * 4 + rp * 2 + 1] * inv);
                *(unsigned*)((char*)Plds + n * 144 + m * 2) = lo | (hi << 16);
            }
    }

    wave_sync();

    f32x4 O[4][4] = {};
#pragma unroll
    for (int ks = 0; ks < 2; ++ks) {
        s16x8 pa[4];
#pragma unroll
        for (int in = 0; in < 4; ++in)
            pa[in] = *(const s16x8*)((const char*)Plds +
                      (in * 16 + rr) * 144 + ks * 64 + g * 16);
#pragma unroll
        for (int jd = 0; jd < 4; ++jd) {
            s16x8 vb;
#pragma unroll
            for (int j = 0; j < 8; ++j) {
                const int k = ks * 32 + g * 8 + j;
                const int byte = (k * 128 + (jd * 16 + rr) * 2) ^ ((k & 7) << 4);
                vb[j] = *(const short*)((const char*)Vlds + byte);
            }
#pragma unroll
            for (int in = 0; in < 4; ++in)
                O[in][jd] = mfma16x16(pa[in], vb, O[in][jd]);
        }
    }

    const long obase = ((long)b * 8192 + p) * 1024 + h * 64;
#pragma unroll
    for (int in = 0; in < 4; ++in)
#pragma unroll
        for (int r = 0; r < 4; ++r) {
            const long n = in * 16 + g * 4 + r;
#pragma unroll
            for (int jd = 0; jd < 4; ++jd) {
                const long d = jd * 16 + rr;
                o[obase + n * (128L * 1024) + d] = f2bf(O[in][jd][r]);
            }
        }
}

// ---------------------------------------------------------------------------
extern "C" void kernel_launch(void* const* d_in, const int* in_sizes, int n_in,
                              void* d_out, int out_size, void* d_ws, size_t ws_size,
                              hipStream_t stream) {
    const float* x    = (const float*)d_in[0];
    const float* Wqkv = (const float*)d_in[1];
    const float* bq   = (const float*)d_in[2];
    const float* Wout = (const float*)d_in[3];
    const float* bo   = (const float*)d_in[4];

    char* ws = (char*)d_ws;
    u16* xb    = (u16*)(ws);                 // 33,554,432 B
    u16* qkv   = (u16*)(ws +  33554432L);    // 100,663,296 B
    u16* ob    = (u16*)(ws + 134217728L);    // 33,554,432 B
    u16* WqkvT = (u16*)(ws + 167772160L);    // 6,291,456 B
    u16* WoutT = (u16*)(ws + 174063616L);    // 2,097,152 B
    const size_t NEEDED = 176160768UL;

    if (ws_size < NEEDED) {
        fill_sentinel<<<2048, 256, 0, stream>>>((float*)d_out, (long)out_size);
        return;
    }

    (void)hipFuncSetAttribute(reinterpret_cast<const void*>(&gemm128<0, 16, 24>),
                              hipFuncAttributeMaxDynamicSharedMemorySize, 65536);
    (void)hipFuncSetAttribute(reinterpret_cast<const void*>(&gemm256<1, 16, 4>),
                              hipFuncAttributeMaxDynamicSharedMemorySize, 131072);

    convert_x<<<2048, 256, 0, stream>>>(x, xb, 16777216L);
    transpose_f32_bf16<<<dim3(96, 32), 256, 0, stream>>>(Wqkv, WqkvT, 1024, 3072);
    transpose_f32_bf16<<<dim3(32, 32), 256, 0, stream>>>(Wout, WoutT, 1024, 1024);

    // qkv = x @ Wqkv + bqkv   (M=16384, N=3072, K=1024): 128x24 = 3072 blocks
    gemm128<0, 16, 24><<<3072, 256, 65536, stream>>>(xb, WqkvT, bq, qkv,
                                                     3072, 1024);

    attn_blocks<<<4096, 64, 0, stream>>>(qkv, ob);

    // out = o @ Wout + bout   (M=16384, N=1024, K=1024): proven R9 path
    gemm256<1, 16, 4><<<256, 512, 131072, stream>>>(ob, WoutT, bo, d_out,
                                                    1024, 1024);
}

// Round 13
// 210.786 us; speedup vs baseline: 1.0743x; 1.0743x over previous
//
#include <hip/hip_runtime.h>
#include <stdint.h>

typedef unsigned short u16;
typedef __attribute__((ext_vector_type(8))) short s16x8;   // 8 x bf16 (4 VGPRs)
typedef __attribute__((ext_vector_type(4))) float f32x4;   // MFMA accumulator

__device__ __forceinline__ f32x4 mfma16x16(s16x8 a, s16x8 b, f32x4 c) {
    return __builtin_amdgcn_mfma_f32_16x16x32_bf16(a, b, c, 0, 0, 0);
}

__device__ __forceinline__ u16 f2bf(float f) {
    union { float f; unsigned u; } c; c.f = f;
    unsigned u = c.u;
    return (u16)((u + 0x7FFFu + ((u >> 16) & 1u)) >> 16);   // RNE
}

// global -> LDS direct 16B load. LDS dest = wave-uniform base + lane*16.
__device__ __forceinline__ void gload16(const void* g, void* l) {
    auto gp = (const __attribute__((address_space(1))) unsigned int*)(g);
    auto lp = (__attribute__((address_space(3))) unsigned int*)(l);
    __builtin_amdgcn_global_load_lds(gp, lp, 16, 0, 0);
}

__device__ __forceinline__ void wave_sync() {
    __builtin_amdgcn_sched_barrier(0);
    asm volatile("s_waitcnt vmcnt(0) lgkmcnt(0)" ::: "memory");
    __builtin_amdgcn_sched_barrier(0);
    __builtin_amdgcn_s_barrier();
    __builtin_amdgcn_sched_barrier(0);
}

// ---------------------------------------------------------------------------
__global__ __launch_bounds__(256) void convert_x(
    const float* __restrict__ src, u16* __restrict__ dst, long n)
{
    const long stride = (long)gridDim.x * 256 * 8;
    for (long i = ((long)blockIdx.x * 256 + threadIdx.x) * 8; i < n; i += stride) {
        const float4 a = *(const float4*)(src + i);
        const float4 b = *(const float4*)(src + i + 4);
        u16 o[8] = { f2bf(a.x), f2bf(a.y), f2bf(a.z), f2bf(a.w),
                     f2bf(b.x), f2bf(b.y), f2bf(b.z), f2bf(b.w) };
        *(s16x8*)(dst + i) = *(const s16x8*)o;
    }
}

__global__ __launch_bounds__(256) void fill_sentinel(float* __restrict__ o, long n)
{
    const long stride = (long)gridDim.x * 256;
    for (long i = (long)blockIdx.x * 256 + threadIdx.x; i < n; i += stride)
        o[i] = 1.0f;
}

__global__ __launch_bounds__(256) void transpose_f32_bf16(
    const float* __restrict__ in, u16* __restrict__ out, int R, int C)
{
    __shared__ u16 t[32][33];
    const int c0 = blockIdx.x * 32, r0 = blockIdx.y * 32;
    const int tx = threadIdx.x & 31, ty = threadIdx.x >> 5;
#pragma unroll
    for (int i = 0; i < 32; i += 8)
        t[ty + i][tx] = f2bf(in[(long)(r0 + ty + i) * C + c0 + tx]);
    __syncthreads();
#pragma unroll
    for (int i = 0; i < 32; i += 8)
        out[(long)(c0 + ty + i) * R + r0 + tx] = t[tx][ty + i];
}

// ---------------------------------------------------------------------------
// 256x256 GEMM, one-full-step-ahead register pipeline (R13 = R12 + fixed
// prologue gate).
// 2 steps per K-tile (BK=64, halves kk0/kk1). Each step:
//   [vmcnt(4) gate; barrier]  (uniform; tail kk0 of t=NT-1 -> vmcnt(0))
//   12 ds_read_b128 -> NEXT step's fragment set (S_next)
//   stage ONE half-tile (4 gload_lds)
//   32 MFMA on CURRENT set (data read a full step ago; its lgkm wait is
//   zero and the 12 new reads drain under the MFMA cluster).
// PROLOGUE GATE = vmcnt(4): certifies t0.h0 AND t0.h1 (R12's vmcnt(8) only
// certified h0, so tile-0 kk0's RD of t0.kk1 read un-landed LDS -> the
// absmax 16.5 failure).
// Stage map: kk0-step stages (t+1).h1; kk1-step stages (t+2).h0.
// Gate ledger (steady): outstanding = 8 at every gate; vmcnt(4) drains the
// needed oldest half-tile. Tail: t=NT-1 kk0 has only 4 outstanding -> vmcnt(0).
// WAR: staged region's last ds_reads are consumed by the MFMA cluster
// preceding the step-start barrier (verified t=0, steady, both tail tiles).
// ---------------------------------------------------------------------------
template <int FP32OUT, int NT, int NBN>
__global__ __launch_bounds__(512, 2) void gemm256(
    const u16* __restrict__ A, const u16* __restrict__ BT,
    const float* __restrict__ bias, void* __restrict__ Cout,
    int N, int K)
{
    extern __shared__ char smem[];          // 131072 B
    char* const As = smem;
    char* const Bs = smem + 65536;

    const int tid  = threadIdx.x;
    const int lane = tid & 63;
    const int wid  = tid >> 6;
    const int rr   = lane & 15, g = lane >> 4;
    const int wr   = wid >> 2;
    const int wc   = wid & 3;

    const int nwg = gridDim.x;
    const int gsw = ((int)blockIdx.x & 7) * (nwg >> 3) + ((int)blockIdx.x >> 3);
    const long m0 = (long)(gsw / NBN) * 256;   // n-fastest within XCD
    const long n0 = (long)(gsw % NBN) * 256;

    const int cl = (tid & 3) ^ ((tid >> 3) & 3);
    const u16* pA0 = A  + (m0 + (tid >> 2)) * (long)K + cl * 8;
    const u16* pA1 = pA0 + 128 * (long)K;
    const u16* pB0 = BT + (n0 + (tid >> 2)) * (long)K + cl * 8;
    const u16* pB1 = pB0 + 128 * (long)K;
    const int sdst = wid * 1024;

    const int xg   = (g ^ ((rr >> 1) & 3)) << 4;
    const int arow = (wr * 128 + rr) * 64 + xg;   // + mf*1024
    const int brow = (wc * 64  + rr) * 64 + xg;   // + nf*1024

#define STA(tt, h) { const long c_ = (long)(tt) * 64 + (h) * 32;              \
        char* d_ = As + (((tt) & 1) * 2 + (h)) * 16384 + sdst;                \
        gload16(pA0 + c_, d_); gload16(pA1 + c_, d_ + 8192); }
#define STB(tt, h) { const long c_ = (long)(tt) * 64 + (h) * 32;              \
        char* d_ = Bs + (((tt) & 1) * 2 + (h)) * 16384 + sdst;                \
        gload16(pB0 + c_, d_); gload16(pB1 + c_, d_ + 8192); }
#define SB() __builtin_amdgcn_sched_barrier(0)
#define RD(Bf, Af, half, bufsel)                                              \
    { _Pragma("unroll") for (int n_ = 0; n_ < 4; ++n_)                        \
          Bf[n_] = *(const s16x8*)(Bs + (bufsel) + (half) + brow + n_ * 1024);\
      _Pragma("unroll") for (int m_ = 0; m_ < 8; ++m_)                        \
          Af[m_] = *(const s16x8*)(As + (bufsel) + (half) + arow + m_ * 1024);}
#define MM(Af, Bf)                                                            \
    { SB(); __builtin_amdgcn_s_setprio(1);                                    \
      _Pragma("unroll") for (int m_ = 0; m_ < 8; ++m_)                        \
      _Pragma("unroll") for (int n_ = 0; n_ < 4; ++n_)                        \
          acc[m_][n_] = mfma16x16(Af[m_], Bf[n_], acc[m_][n_]);               \
      __builtin_amdgcn_s_setprio(0); SB(); }

    f32x4 acc[8][4] = {};
    s16x8 B0[4], A0[8], B1[4], A1[8];

    // prologue: stage t0.h0, t0.h1, t1.h0 (12 loads); gate vmcnt(4) so BOTH
    // t0 halves are landed (leaves t1.h0 in flight); read S0 <- t0.kk0.
    STA(0, 0); STB(0, 0); STA(0, 1); STB(0, 1); STA(1, 0); STB(1, 0);
    asm volatile("s_waitcnt vmcnt(4)" ::: "memory");
    SB(); __builtin_amdgcn_s_barrier(); SB();
    RD(B0, A0, 0, 0);                       // S0 <- t0.kk0

    for (int t = 0; t < NT; ++t) {
        const int ab = (t & 1) * 32768;
        const int nb = ((t + 1) & 1) * 32768;

        // ---- step kk0: reads S1 <- t.kk1; stage (t+1).h1; MFMA on S0
        if (t > 0) {
            if (t == NT - 1) { asm volatile("s_waitcnt vmcnt(0)" ::: "memory"); }
            else             { asm volatile("s_waitcnt vmcnt(4)" ::: "memory"); }
            SB(); __builtin_amdgcn_s_barrier(); SB();
        }
        RD(B1, A1, 16384, ab);
        SB();
        if (t + 1 < NT) { STA(t + 1, 1); STB(t + 1, 1); }
        MM(A0, B0);

        // ---- step kk1: reads S0 <- (t+1).kk0; stage (t+2).h0; MFMA on S1
        if (t < NT - 1) {
            asm volatile("s_waitcnt vmcnt(4)" ::: "memory");
            SB(); __builtin_amdgcn_s_barrier(); SB();
            RD(B0, A0, 0, nb);
            SB();
            if (t + 2 < NT) { STA(t + 2, 0); STB(t + 2, 0); }
        }
        MM(A1, B1);
    }
#undef STA
#undef STB
#undef SB
#undef RD
#undef MM

    // epilogue: n innermost (L2 write-merge)
    float bv[4];
#pragma unroll
    for (int n = 0; n < 4; ++n)
        bv[n] = bias[n0 + wc * 64 + n * 16 + rr];
#pragma unroll
    for (int m = 0; m < 8; ++m) {
        const long rb = m0 + wr * 128 + m * 16 + g * 4;
#pragma unroll
        for (int r = 0; r < 4; ++r) {
            const long rowoff = (rb + r) * N + n0 + wc * 64 + rr;
#pragma unroll
            for (int n = 0; n < 4; ++n) {
                const float v = acc[m][n][r] + bv[n];
                if (FP32OUT) ((float*)Cout)[rowoff + n * 16] = v;
                else         ((u16*)Cout)[rowoff + n * 16] = f2bf(v);
            }
        }
    }
}

// ---------------------------------------------------------------------------
// Factored attention: one wave per (b, h, p). Attention over NB=64 blocks.
// ---------------------------------------------------------------------------
__global__ __launch_bounds__(64) void attn_blocks(
    const u16* __restrict__ qkv, u16* __restrict__ o)
{
    __shared__ u16 Vlds[64 * 64];
    __shared__ u16 Plds[64 * 72];
    const int bid = blockIdx.x;
    const int b = bid >> 11;
    const int h = (bid >> 7) & 15;
    const int p = bid & 127;
    const int lane = threadIdx.x;
    const int rr = lane & 15, g = lane >> 4;
    const long NSTR = 128L * 3072;
    const long base = ((long)b * 8192 + p) * 3072 + h * 64;

    {
        const int vrow = lane >> 3;
        const int vchunk = (lane & 7) ^ (vrow & 7);
#pragma unroll
        for (int q = 0; q < 8; ++q)
            gload16(qkv + base + (long)(q * 8 + vrow) * NSTR + 2048 + vchunk * 8,
                    (char*)Vlds + q * 1024);
    }

    s16x8 kf[4][2], qf[4][2];
#pragma unroll
    for (int t = 0; t < 4; ++t)
#pragma unroll
        for (int ks = 0; ks < 2; ++ks) {
            const long roff = base + (long)(t * 16 + rr) * NSTR + ks * 32 + g * 8;
            kf[t][ks] = *(const s16x8*)(qkv + roff + 1024);
            qf[t][ks] = *(const s16x8*)(qkv + roff);
        }

    f32x4 T[4][4] = {};
#pragma unroll
    for (int ks = 0; ks < 2; ++ks)
#pragma unroll
        for (int i = 0; i < 4; ++i)
#pragma unroll
            for (int jn = 0; jn < 4; ++jn)
                T[i][jn] = mfma16x16(kf[i][ks], qf[jn][ks], T[i][jn]);

    const float scale = 0.125f;
#pragma unroll
    for (int jn = 0; jn < 4; ++jn) {
        const int n = jn * 16 + rr;
        float pv[16];
        float mx = -3e38f;
#pragma unroll
        for (int i = 0; i < 4; ++i)
#pragma unroll
            for (int r = 0; r < 4; ++r) {
                const int m = i * 16 + g * 4 + r;
                const float s = (m <= n) ? T[i][jn][r] * scale : -3e38f;
                pv[i * 4 + r] = s;
                mx = fmaxf(mx, s);
            }
        mx = fmaxf(mx, __shfl_xor(mx, 16));
        mx = fmaxf(mx, __shfl_xor(mx, 32));
        float sum = 0.f;
#pragma unroll
        for (int t = 0; t < 16; ++t) {
            const float e = (pv[t] > -1e30f) ? __expf(pv[t] - mx) : 0.f;
            pv[t] = e;
            sum += e;
        }
        sum += __shfl_xor(sum, 16);
        sum += __shfl_xor(sum, 32);
        const float inv = 1.f / sum;
#pragma unroll
        for (int i = 0; i < 4; ++i)
#pragma unroll
            for (int rp = 0; rp < 2; ++rp) {
                const int m = i * 16 + g * 4 + rp * 2;
                const unsigned lo = f2bf(pv[i * 4 + rp * 2] * inv);
                const unsigned hi = f2bf(pv[i * 4 + rp * 2 + 1] * inv);
                *(unsigned*)((char*)Plds + n * 144 + m * 2) = lo | (hi << 16);
            }
    }

    wave_sync();

    f32x4 O[4][4] = {};
#pragma unroll
    for (int ks = 0; ks < 2; ++ks) {
        s16x8 pa[4];
#pragma unroll
        for (int in = 0; in < 4; ++in)
            pa[in] = *(const s16x8*)((const char*)Plds +
                      (in * 16 + rr) * 144 + ks * 64 + g * 16);
#pragma unroll
        for (int jd = 0; jd < 4; ++jd) {
            s16x8 vb;
#pragma unroll
            for (int j = 0; j < 8; ++j) {
                const int k = ks * 32 + g * 8 + j;
                const int byte = (k * 128 + (jd * 16 + rr) * 2) ^ ((k & 7) << 4);
                vb[j] = *(const short*)((const char*)Vlds + byte);
            }
#pragma unroll
            for (int in = 0; in < 4; ++in)
                O[in][jd] = mfma16x16(pa[in], vb, O[in][jd]);
        }
    }

    const long obase = ((long)b * 8192 + p) * 1024 + h * 64;
#pragma unroll
    for (int in = 0; in < 4; ++in)
#pragma unroll
        for (int r = 0; r < 4; ++r) {
            const long n = in * 16 + g * 4 + r;
#pragma unroll
            for (int jd = 0; jd < 4; ++jd) {
                const long d = jd * 16 + rr;
                o[obase + n * (128L * 1024) + d] = f2bf(O[in][jd][r]);
            }
        }
}

// ---------------------------------------------------------------------------
extern "C" void kernel_launch(void* const* d_in, const int* in_sizes, int n_in,
                              void* d_out, int out_size, void* d_ws, size_t ws_size,
                              hipStream_t stream) {
    const float* x    = (const float*)d_in[0];
    const float* Wqkv = (const float*)d_in[1];
    const float* bq   = (const float*)d_in[2];
    const float* Wout = (const float*)d_in[3];
    const float* bo   = (const float*)d_in[4];

    char* ws = (char*)d_ws;
    u16* xb    = (u16*)(ws);                 // 33,554,432 B
    u16* qkv   = (u16*)(ws +  33554432L);    // 100,663,296 B
    u16* ob    = (u16*)(ws + 134217728L);    // 33,554,432 B
    u16* WqkvT = (u16*)(ws + 167772160L);    // 6,291,456 B
    u16* WoutT = (u16*)(ws + 174063616L);    // 2,097,152 B
    const size_t NEEDED = 176160768UL;

    if (ws_size < NEEDED) {
        fill_sentinel<<<2048, 256, 0, stream>>>((float*)d_out, (long)out_size);
        return;
    }

    (void)hipFuncSetAttribute(reinterpret_cast<const void*>(&gemm256<0, 16, 12>),
                              hipFuncAttributeMaxDynamicSharedMemorySize, 131072);
    (void)hipFuncSetAttribute(reinterpret_cast<const void*>(&gemm256<1, 16, 4>),
                              hipFuncAttributeMaxDynamicSharedMemorySize, 131072);

    convert_x<<<2048, 256, 0, stream>>>(x, xb, 16777216L);
    transpose_f32_bf16<<<dim3(96, 32), 256, 0, stream>>>(Wqkv, WqkvT, 1024, 3072);
    transpose_f32_bf16<<<dim3(32, 32), 256, 0, stream>>>(Wout, WoutT, 1024, 1024);

    // qkv = x @ Wqkv + bqkv   (M=16384, N=3072, K=1024)
    gemm256<0, 16, 12><<<768, 512, 131072, stream>>>(xb, WqkvT, bq, qkv,
                                                     3072, 1024);

    attn_blocks<<<4096, 64, 0, stream>>>(qkv, ob);

    // out = o @ Wout + bout   (M=16384, N=1024, K=1024)
    gemm256<1, 16, 4><<<256, 512, 131072, stream>>>(ob, WoutT, bo, d_out,
                                                    1024, 1024);
}

// Round 14
// 196.614 us; speedup vs baseline: 1.1517x; 1.0721x over previous
//
#include <hip/hip_runtime.h>
#include <stdint.h>

typedef unsigned short u16;
typedef __attribute__((ext_vector_type(8))) short s16x8;   // 8 x bf16 (4 VGPRs)
typedef __attribute__((ext_vector_type(4))) float f32x4;   // MFMA accumulator

__device__ __forceinline__ f32x4 mfma16x16(s16x8 a, s16x8 b, f32x4 c) {
    return __builtin_amdgcn_mfma_f32_16x16x32_bf16(a, b, c, 0, 0, 0);
}

__device__ __forceinline__ u16 f2bf(float f) {
    union { float f; unsigned u; } c; c.f = f;
    unsigned u = c.u;
    return (u16)((u + 0x7FFFu + ((u >> 16) & 1u)) >> 16);   // RNE
}

// global -> LDS direct 16B load. LDS dest = wave-uniform base + lane*16.
__device__ __forceinline__ void gload16(const void* g, void* l) {
    auto gp = (const __attribute__((address_space(1))) unsigned int*)(g);
    auto lp = (__attribute__((address_space(3))) unsigned int*)(l);
    __builtin_amdgcn_global_load_lds(gp, lp, 16, 0, 0);
}

__device__ __forceinline__ void wave_sync() {
    __builtin_amdgcn_sched_barrier(0);
    asm volatile("s_waitcnt vmcnt(0) lgkmcnt(0)" ::: "memory");
    __builtin_amdgcn_sched_barrier(0);
    __builtin_amdgcn_s_barrier();
    __builtin_amdgcn_sched_barrier(0);
}

// ---------------------------------------------------------------------------
__global__ __launch_bounds__(256) void convert_x(
    const float* __restrict__ src, u16* __restrict__ dst, long n)
{
    const long stride = (long)gridDim.x * 256 * 8;
    for (long i = ((long)blockIdx.x * 256 + threadIdx.x) * 8; i < n; i += stride) {
        const float4 a = *(const float4*)(src + i);
        const float4 b = *(const float4*)(src + i + 4);
        u16 o[8] = { f2bf(a.x), f2bf(a.y), f2bf(a.z), f2bf(a.w),
                     f2bf(b.x), f2bf(b.y), f2bf(b.z), f2bf(b.w) };
        *(s16x8*)(dst + i) = *(const s16x8*)o;
    }
}

__global__ __launch_bounds__(256) void fill_sentinel(float* __restrict__ o, long n)
{
    const long stride = (long)gridDim.x * 256;
    for (long i = (long)blockIdx.x * 256 + threadIdx.x; i < n; i += stride)
        o[i] = 1.0f;
}

__global__ __launch_bounds__(256) void transpose_f32_bf16(
    const float* __restrict__ in, u16* __restrict__ out, int R, int C)
{
    __shared__ u16 t[32][33];
    const int c0 = blockIdx.x * 32, r0 = blockIdx.y * 32;
    const int tx = threadIdx.x & 31, ty = threadIdx.x >> 5;
#pragma unroll
    for (int i = 0; i < 32; i += 8)
        t[ty + i][tx] = f2bf(in[(long)(r0 + ty + i) * C + c0 + tx]);
    __syncthreads();
#pragma unroll
    for (int i = 0; i < 32; i += 8)
        out[(long)(c0 + ty + i) * R + r0 + tx] = t[tx][ty + i];
}

// ---------------------------------------------------------------------------
// 256x256 GEMM, single-barrier-per-tile schedule (R14).
// Key change vs R9: tile t stages ALL of tile t+1 (8 gloads, OPPOSITE LDS
// parity) at tile start -> staging never touches the region being read ->
// the mid-tile WAR barrier is deleted. One barrier + one vmcnt(0) per tile;
// the vmcnt(0) is free (loads issued a full tile ~5000 cyc earlier).
// Without the mid barrier, waves skew within the tile so one wave's MFMA
// covers another's ds_read burst (attacks the phase-lockstep that capped
// MfmaUtil at 40%). Within-tile register pipeline identical to R9: every
// cluster's operands are issued >=1 cluster ahead except the tile's first.
// WAR safety: a wave reaches the boundary barrier only after its MFMA
// clusters' lgkm waits, i.e. all its parity-p reads completed; after the
// barrier all waves' reads are done, so tile t+1 may DMA into parity p.
// ---------------------------------------------------------------------------
template <int FP32OUT, int NT, int NBN>
__global__ __launch_bounds__(512, 2) void gemm256(
    const u16* __restrict__ A, const u16* __restrict__ BT,
    const float* __restrict__ bias, void* __restrict__ Cout,
    int N, int K)
{
    extern __shared__ char smem[];          // 131072 B
    char* const As = smem;
    char* const Bs = smem + 65536;

    const int tid  = threadIdx.x;
    const int lane = tid & 63;
    const int wid  = tid >> 6;
    const int rr   = lane & 15, g = lane >> 4;
    const int wr   = wid >> 2;
    const int wc   = wid & 3;

    const int nwg = gridDim.x;
    const int gsw = ((int)blockIdx.x & 7) * (nwg >> 3) + ((int)blockIdx.x >> 3);
    const long m0 = (long)(gsw / NBN) * 256;   // n-fastest within XCD
    const long n0 = (long)(gsw % NBN) * 256;

    const int cl = (tid & 3) ^ ((tid >> 3) & 3);
    const u16* pA0 = A  + (m0 + (tid >> 2)) * (long)K + cl * 8;
    const u16* pA1 = pA0 + 128 * (long)K;
    const u16* pB0 = BT + (n0 + (tid >> 2)) * (long)K + cl * 8;
    const u16* pB1 = pB0 + 128 * (long)K;
    const int sdst = wid * 1024;

    const int xg   = (g ^ ((rr >> 1) & 3)) << 4;
    const int arow = (wr * 128 + rr) * 64 + xg;   // + mf*1024
    const int brow = (wc * 64  + rr) * 64 + xg;   // + nf*1024

#define STA(tt, h) { const long c_ = (long)(tt) * 64 + (h) * 32;              \
        char* d_ = As + (((tt) & 1) * 2 + (h)) * 16384 + sdst;                \
        gload16(pA0 + c_, d_); gload16(pA1 + c_, d_ + 8192); }
#define STB(tt, h) { const long c_ = (long)(tt) * 64 + (h) * 32;              \
        char* d_ = Bs + (((tt) & 1) * 2 + (h)) * 16384 + sdst;                \
        gload16(pB0 + c_, d_); gload16(pB1 + c_, d_ + 8192); }
#define SB() __builtin_amdgcn_sched_barrier(0)
#define MM(Af, Bf, mb)                                                        \
    { SB(); __builtin_amdgcn_s_setprio(1);                                    \
      _Pragma("unroll") for (int m_ = 0; m_ < 4; ++m_)                        \
      _Pragma("unroll") for (int n_ = 0; n_ < 4; ++n_)                        \
          acc[(mb) + m_][n_] = mfma16x16(Af[m_], Bf[n_], acc[(mb) + m_][n_]); \
      __builtin_amdgcn_s_setprio(0); SB(); }

    f32x4 acc[8][4] = {};

    // prologue: stage all of t0, drain, barrier
    STA(0, 0); STB(0, 0); STA(0, 1); STB(0, 1);
    asm volatile("s_waitcnt vmcnt(0)" ::: "memory");
    SB(); __builtin_amdgcn_s_barrier(); SB();

    for (int t = 0; t < NT; ++t) {
        const int ab = (t & 1) * 32768;
        s16x8 fB0[4], fA0[4], fA1[4], fB1[4], fA2[4], fA3[4];

        // stage ALL of tile t+1 (opposite parity -- no WAR with this tile)
        if (t + 1 < NT) { STA(t + 1, 0); STB(t + 1, 0);
                          STA(t + 1, 1); STB(t + 1, 1); }
        SB();

        // kk0 reads (12)
#pragma unroll
        for (int n = 0; n < 4; ++n)
            fB0[n] = *(const s16x8*)(Bs + ab + brow + n * 1024);
#pragma unroll
        for (int m = 0; m < 4; ++m)
            fA0[m] = *(const s16x8*)(As + ab + arow + m * 1024);
#pragma unroll
        for (int m = 0; m < 4; ++m)
            fA1[m] = *(const s16x8*)(As + ab + arow + (m + 4) * 1024);
        MM(fA0, fB0, 0);                       // waits fB0+fA0; fA1 in flight

        // kk1 reads (8) under cluster1
#pragma unroll
        for (int n = 0; n < 4; ++n)
            fB1[n] = *(const s16x8*)(Bs + ab + 16384 + brow + n * 1024);
#pragma unroll
        for (int m = 0; m < 4; ++m)
            fA2[m] = *(const s16x8*)(As + ab + 16384 + arow + m * 1024);
        MM(fA1, fB0, 4);                       // waits fA1; fB1+fA2 in flight

        // kk1 A m4-7 (4) under cluster2
#pragma unroll
        for (int m = 0; m < 4; ++m)
            fA3[m] = *(const s16x8*)(As + ab + 16384 + arow + (m + 4) * 1024);
        MM(fA2, fB1, 0);                       // waits fB1+fA2; fA3 in flight
        MM(fA3, fB1, 4);                       // waits fA3 (covered)

        // boundary: free vmcnt(0) (stages issued a full tile ago), barrier
        if (t < NT - 1) {
            asm volatile("s_waitcnt vmcnt(0)" ::: "memory");
            SB(); __builtin_amdgcn_s_barrier(); SB();
        }
    }
#undef STA
#undef STB
#undef SB
#undef MM

    // epilogue: n innermost (L2 write-merge)
    float bv[4];
#pragma unroll
    for (int n = 0; n < 4; ++n)
        bv[n] = bias[n0 + wc * 64 + n * 16 + rr];
#pragma unroll
    for (int m = 0; m < 8; ++m) {
        const long rb = m0 + wr * 128 + m * 16 + g * 4;
#pragma unroll
        for (int r = 0; r < 4; ++r) {
            const long rowoff = (rb + r) * N + n0 + wc * 64 + rr;
#pragma unroll
            for (int n = 0; n < 4; ++n) {
                const float v = acc[m][n][r] + bv[n];
                if (FP32OUT) ((float*)Cout)[rowoff + n * 16] = v;
                else         ((u16*)Cout)[rowoff + n * 16] = f2bf(v);
            }
        }
    }
}

// ---------------------------------------------------------------------------
// Factored attention: one wave per (b, h, p). Attention over NB=64 blocks.
// ---------------------------------------------------------------------------
__global__ __launch_bounds__(64) void attn_blocks(
    const u16* __restrict__ qkv, u16* __restrict__ o)
{
    __shared__ u16 Vlds[64 * 64];
    __shared__ u16 Plds[64 * 72];
    const int bid = blockIdx.x;
    const int b = bid >> 11;
    const int h = (bid >> 7) & 15;
    const int p = bid & 127;
    const int lane = threadIdx.x;
    const int rr = lane & 15, g = lane >> 4;
    const long NSTR = 128L * 3072;
    const long base = ((long)b * 8192 + p) * 3072 + h * 64;

    {
        const int vrow = lane >> 3;
        const int vchunk = (lane & 7) ^ (vrow & 7);
#pragma unroll
        for (int q = 0; q < 8; ++q)
            gload16(qkv + base + (long)(q * 8 + vrow) * NSTR + 2048 + vchunk * 8,
                    (char*)Vlds + q * 1024);
    }

    s16x8 kf[4][2], qf[4][2];
#pragma unroll
    for (int t = 0; t < 4; ++t)
#pragma unroll
        for (int ks = 0; ks < 2; ++ks) {
            const long roff = base + (long)(t * 16 + rr) * NSTR + ks * 32 + g * 8;
            kf[t][ks] = *(const s16x8*)(qkv + roff + 1024);
            qf[t][ks] = *(const s16x8*)(qkv + roff);
        }

    f32x4 T[4][4] = {};
#pragma unroll
    for (int ks = 0; ks < 2; ++ks)
#pragma unroll
        for (int i = 0; i < 4; ++i)
#pragma unroll
            for (int jn = 0; jn < 4; ++jn)
                T[i][jn] = mfma16x16(kf[i][ks], qf[jn][ks], T[i][jn]);

    const float scale = 0.125f;
#pragma unroll
    for (int jn = 0; jn < 4; ++jn) {
        const int n = jn * 16 + rr;
        float pv[16];
        float mx = -3e38f;
#pragma unroll
        for (int i = 0; i < 4; ++i)
#pragma unroll
            for (int r = 0; r < 4; ++r) {
                const int m = i * 16 + g * 4 + r;
                const float s = (m <= n) ? T[i][jn][r] * scale : -3e38f;
                pv[i * 4 + r] = s;
                mx = fmaxf(mx, s);
            }
        mx = fmaxf(mx, __shfl_xor(mx, 16));
        mx = fmaxf(mx, __shfl_xor(mx, 32));
        float sum = 0.f;
#pragma unroll
        for (int t = 0; t < 16; ++t) {
            const float e = (pv[t] > -1e30f) ? __expf(pv[t] - mx) : 0.f;
            pv[t] = e;
            sum += e;
        }
        sum += __shfl_xor(sum, 16);
        sum += __shfl_xor(sum, 32);
        const float inv = 1.f / sum;
#pragma unroll
        for (int i = 0; i < 4; ++i)
#pragma unroll
            for (int rp = 0; rp < 2; ++rp) {
                const int m = i * 16 + g * 4 + rp * 2;
                const unsigned lo = f2bf(pv[i * 4 + rp * 2] * inv);
                const unsigned hi = f2bf(pv[i * 4 + rp * 2 + 1] * inv);
                *(unsigned*)((char*)Plds + n * 144 + m * 2) = lo | (hi << 16);
            }
    }

    wave_sync();

    f32x4 O[4][4] = {};
#pragma unroll
    for (int ks = 0; ks < 2; ++ks) {
        s16x8 pa[4];
#pragma unroll
        for (int in = 0; in < 4; ++in)
            pa[in] = *(const s16x8*)((const char*)Plds +
                      (in * 16 + rr) * 144 + ks * 64 + g * 16);
#pragma unroll
        for (int jd = 0; jd < 4; ++jd) {
            s16x8 vb;
#pragma unroll
            for (int j = 0; j < 8; ++j) {
                const int k = ks * 32 + g * 8 + j;
                const int byte = (k * 128 + (jd * 16 + rr) * 2) ^ ((k & 7) << 4);
                vb[j] = *(const short*)((const char*)Vlds + byte);
            }
#pragma unroll
            for (int in = 0; in < 4; ++in)
                O[in][jd] = mfma16x16(pa[in], vb, O[in][jd]);
        }
    }

    const long obase = ((long)b * 8192 + p) * 1024 + h * 64;
#pragma unroll
    for (int in = 0; in < 4; ++in)
#pragma unroll
        for (int r = 0; r < 4; ++r) {
            const long n = in * 16 + g * 4 + r;
#pragma unroll
            for (int jd = 0; jd < 4; ++jd) {
                const long d = jd * 16 + rr;
                o[obase + n * (128L * 1024) + d] = f2bf(O[in][jd][r]);
            }
        }
}

// ---------------------------------------------------------------------------
extern "C" void kernel_launch(void* const* d_in, const int* in_sizes, int n_in,
                              void* d_out, int out_size, void* d_ws, size_t ws_size,
                              hipStream_t stream) {
    const float* x    = (const float*)d_in[0];
    const float* Wqkv = (const float*)d_in[1];
    const float* bq   = (const float*)d_in[2];
    const float* Wout = (const float*)d_in[3];
    const float* bo   = (const float*)d_in[4];

    char* ws = (char*)d_ws;
    u16* xb    = (u16*)(ws);                 // 33,554,432 B
    u16* qkv   = (u16*)(ws +  33554432L);    // 100,663,296 B
    u16* ob    = (u16*)(ws + 134217728L);    // 33,554,432 B
    u16* WqkvT = (u16*)(ws + 167772160L);    // 6,291,456 B
    u16* WoutT = (u16*)(ws + 174063616L);    // 2,097,152 B
    const size_t NEEDED = 176160768UL;

    if (ws_size < NEEDED) {
        fill_sentinel<<<2048, 256, 0, stream>>>((float*)d_out, (long)out_size);
        return;
    }

    (void)hipFuncSetAttribute(reinterpret_cast<const void*>(&gemm256<0, 16, 12>),
                              hipFuncAttributeMaxDynamicSharedMemorySize, 131072);
    (void)hipFuncSetAttribute(reinterpret_cast<const void*>(&gemm256<1, 16, 4>),
                              hipFuncAttributeMaxDynamicSharedMemorySize, 131072);

    convert_x<<<2048, 256, 0, stream>>>(x, xb, 16777216L);
    transpose_f32_bf16<<<dim3(96, 32), 256, 0, stream>>>(Wqkv, WqkvT, 1024, 3072);
    transpose_f32_bf16<<<dim3(32, 32), 256, 0, stream>>>(Wout, WoutT, 1024, 1024);

    // qkv = x @ Wqkv + bqkv   (M=16384, N=3072, K=1024)
    gemm256<0, 16, 12><<<768, 512, 131072, stream>>>(xb, WqkvT, bq, qkv,
                                                     3072, 1024);

    attn_blocks<<<4096, 64, 0, stream>>>(qkv, ob);

    // out = o @ Wout + bout   (M=16384, N=1024, K=1024)
    gemm256<1, 16, 4><<<256, 512, 131072, stream>>>(ob, WoutT, bo, d_out,
                                                    1024, 1024);
}